// Round 1
// baseline (427.932 us; speedup 1.0000x reference)
//
#include <hip/hip_runtime.h>
#include <hip/hip_bf16.h>
#include <math.h>

#define B_DIM 4
#define C_DIM 256
#define CQK_DIM 32
#define N_POS 4096

typedef unsigned short u16;
typedef __attribute__((ext_vector_type(8))) short bf16x8;
typedef __attribute__((ext_vector_type(4))) float f32x4;

__device__ __forceinline__ u16 f32_to_bf16_rn(float f) {
    union { float f; unsigned int u; } v; v.f = f;
    unsigned int u = v.u;
    u += 0x7fffu + ((u >> 16) & 1u);
    return (u16)(u >> 16);
}
__device__ __forceinline__ float bf16_to_f32(u16 h) {
    union { unsigned int u; float f; } v; v.u = ((unsigned int)h) << 16;
    return v.f;
}

// ---------------------------------------------------------------------------
// Projection: q = Wq x + bq, k = Wk x + bk (fp32, split to bf16 hi/lo,
// stored [b, n, 32] position-major), v = Wv x + bv (bf16, stored [b, c, n]).
// ---------------------------------------------------------------------------
__global__ __launch_bounds__(256) void proj_kernel(
    const float* __restrict__ x,
    const float* __restrict__ Wq, const float* __restrict__ bq,
    const float* __restrict__ Wk, const float* __restrict__ bk,
    const float* __restrict__ Wv, const float* __restrict__ bv,
    u16* __restrict__ qhi, u16* __restrict__ qlo,
    u16* __restrict__ khi, u16* __restrict__ klo,
    u16* __restrict__ vbf)
{
    const int TI = 32;
    __shared__ float xs[C_DIM][TI];   // 32 KB
    const int t  = threadIdx.x;
    const int blk = blockIdx.x;       // 0..511
    const int b  = blk >> 7;
    const int n0 = (blk & 127) * TI;
    const float* xb = x + (size_t)b * C_DIM * N_POS;

    for (int idx = t; idx < C_DIM * TI; idx += 256) {
        int c = idx >> 5, ii = idx & 31;
        xs[c][ii] = xb[(size_t)c * N_POS + n0 + ii];
    }
    __syncthreads();

    // ---- V phase: thread t -> output channel t, 32 positions
    {
        float acc[TI];
        #pragma unroll
        for (int ii = 0; ii < TI; ++ii) acc[ii] = 0.f;
        const float4* wrow = (const float4*)(Wv + t * C_DIM);
        for (int c4 = 0; c4 < C_DIM / 4; ++c4) {
            float4 w4 = wrow[c4];
            #pragma unroll
            for (int u = 0; u < 4; ++u) {
                int c = c4 * 4 + u;
                float w = (u == 0) ? w4.x : (u == 1) ? w4.y : (u == 2) ? w4.z : w4.w;
                const float4* xr = (const float4*)&xs[c][0];
                #pragma unroll
                for (int q8 = 0; q8 < TI / 4; ++q8) {
                    float4 xv = xr[q8];
                    acc[q8 * 4 + 0] += w * xv.x;
                    acc[q8 * 4 + 1] += w * xv.y;
                    acc[q8 * 4 + 2] += w * xv.z;
                    acc[q8 * 4 + 3] += w * xv.w;
                }
            }
        }
        float bias = bv[t];
        u16* dst = vbf + ((size_t)b * C_DIM + t) * N_POS + n0;
        #pragma unroll
        for (int ii = 0; ii < TI; ++ii) dst[ii] = f32_to_bf16_rn(acc[ii] + bias);
    }

    // ---- Q/K phase: o = t&63 (0..31 -> q, 32..63 -> k), pos group (t>>6)*8
    {
        int o  = t & 63;
        int ig = (t >> 6) * 8;
        const float* wr = (o < 32) ? (Wq + o * C_DIM) : (Wk + (o - 32) * C_DIM);
        float bias = (o < 32) ? bq[o] : bk[o - 32];
        float acc[8];
        #pragma unroll
        for (int ii = 0; ii < 8; ++ii) acc[ii] = 0.f;
        const float4* wrow = (const float4*)wr;
        for (int c4 = 0; c4 < C_DIM / 4; ++c4) {
            float4 w4 = wrow[c4];
            #pragma unroll
            for (int u = 0; u < 4; ++u) {
                int c = c4 * 4 + u;
                float w = (u == 0) ? w4.x : (u == 1) ? w4.y : (u == 2) ? w4.z : w4.w;
                float4 xa = *(const float4*)&xs[c][ig];
                float4 xc = *(const float4*)&xs[c][ig + 4];
                acc[0] += w * xa.x; acc[1] += w * xa.y;
                acc[2] += w * xa.z; acc[3] += w * xa.w;
                acc[4] += w * xc.x; acc[5] += w * xc.y;
                acc[6] += w * xc.z; acc[7] += w * xc.w;
            }
        }
        #pragma unroll
        for (int ii = 0; ii < 8; ++ii) {
            float val = acc[ii] + bias;
            u16 hi = f32_to_bf16_rn(val);
            u16 lo = f32_to_bf16_rn(val - bf16_to_f32(hi));
            size_t base = ((size_t)b * N_POS + (n0 + ig + ii)) * CQK_DIM + (o & 31);
            if (o < 32) { qhi[base] = hi; qlo[base] = lo; }
            else        { khi[base] = hi; klo[base] = lo; }
        }
    }
}

// ---------------------------------------------------------------------------
// Flash attention: each wave owns 16 query rows; online softmax; 3-pass
// hi/lo MFMA for S = q k^T (fp32-accurate logits); bf16 MFMA for O += P V.
// No __syncthreads in the K-loop: waves are fully independent.
// ---------------------------------------------------------------------------
__global__ __launch_bounds__(256) void flash_kernel(
    const u16* __restrict__ qhi, const u16* __restrict__ qlo,
    const u16* __restrict__ khi, const u16* __restrict__ klo,
    const u16* __restrict__ vbf,
    const float* __restrict__ x, float* __restrict__ out)
{
    // per-wave P staging: 16 rows x 64 cols, row stride 72 ushorts (144 B:
    // 16B-aligned for ds_read_b128, 2-way banks on reads)
    __shared__ u16   pbuf[4][16 * 72];   // 9216 B
    // per-wave epilogue transpose: 16 rows x (128+1) floats, 2 c-halves
    __shared__ float epi[4][16 * 129];   // 33024 B

    const int t    = threadIdx.x;
    const int wave = t >> 6;
    const int lane = t & 63;
    const int n16  = lane & 15;
    const int quad = lane >> 4;

    // XCD-aware swizzle: blocks on the same XCD (idx mod 8) share a batch ->
    // that XCD's L2 holds one batch's K (128 KB x2) + V (2 MB) bf16.
    const int idx   = blockIdx.x;            // 0..255
    const int xcd   = idx & 7;
    const int b     = xcd & 3;
    const int itile = ((idx >> 3) << 1) | (xcd >> 2);   // 0..63
    const int i0    = itile * 64 + wave * 16;           // wave's 16 rows

    // Q A-fragments (A[m=lane&15][k=quad*8+j]), loaded once
    const u16* qhp = qhi + ((size_t)b * N_POS + i0 + n16) * CQK_DIM + quad * 8;
    const u16* qlp = qlo + ((size_t)b * N_POS + i0 + n16) * CQK_DIM + quad * 8;
    bf16x8 qh = *(const bf16x8*)qhp;
    bf16x8 ql = *(const bf16x8*)qlp;

    f32x4 O[16];
    #pragma unroll
    for (int cb = 0; cb < 16; ++cb) O[cb] = (f32x4){0.f, 0.f, 0.f, 0.f};
    float m_r[4], l_r[4];
    #pragma unroll
    for (int r = 0; r < 4; ++r) { m_r[r] = -INFINITY; l_r[r] = 0.f; }

    const u16* khb = khi + (size_t)b * N_POS * CQK_DIM;
    const u16* klb = klo + (size_t)b * N_POS * CQK_DIM;
    const u16* vb  = vbf + (size_t)b * C_DIM * N_POS;
    u16* pb = pbuf[wave];

    for (int j0 = 0; j0 < N_POS; j0 += 64) {
        // ---- S = q k^T for 4 j-blocks of 16 (hi*hi + hi*lo + lo*hi)
        f32x4 s[4];
        #pragma unroll
        for (int jb = 0; jb < 4; ++jb) {
            const int j = j0 + jb * 16 + n16;  // B[n=lane&15][k=quad*8+jj]
            bf16x8 kh = *(const bf16x8*)(khb + (size_t)j * CQK_DIM + quad * 8);
            bf16x8 kl = *(const bf16x8*)(klb + (size_t)j * CQK_DIM + quad * 8);
            f32x4 acc = (f32x4){0.f, 0.f, 0.f, 0.f};
            acc = __builtin_amdgcn_mfma_f32_16x16x32_bf16(qh, kh, acc, 0, 0, 0);
            acc = __builtin_amdgcn_mfma_f32_16x16x32_bf16(qh, kl, acc, 0, 0, 0);
            acc = __builtin_amdgcn_mfma_f32_16x16x32_bf16(ql, kh, acc, 0, 0, 0);
            s[jb] = acc;
        }
        // ---- online softmax. C-layout: row = quad*4+r, col = n16.
        // Row i lives across the 16 lanes of its quad -> shfl_xor 1,2,4,8.
        float mt[4], rs[4], alpha[4];
        #pragma unroll
        for (int r = 0; r < 4; ++r)
            mt[r] = fmaxf(fmaxf(s[0][r], s[1][r]), fmaxf(s[2][r], s[3][r]));
        #pragma unroll
        for (int off = 1; off <= 8; off <<= 1) {
            #pragma unroll
            for (int r = 0; r < 4; ++r)
                mt[r] = fmaxf(mt[r], __shfl_xor(mt[r], off, 64));
        }
        #pragma unroll
        for (int r = 0; r < 4; ++r) {
            float mn = fmaxf(m_r[r], mt[r]);
            alpha[r] = __expf(m_r[r] - mn);   // first iter: exp(-inf)=0
            m_r[r] = mn;
            rs[r] = 0.f;
        }
        #pragma unroll
        for (int jb = 0; jb < 4; ++jb) {
            #pragma unroll
            for (int r = 0; r < 4; ++r) {
                float p = __expf(s[jb][r] - m_r[r]);
                s[jb][r] = p;
                rs[r] += p;
            }
        }
        #pragma unroll
        for (int off = 1; off <= 8; off <<= 1) {
            #pragma unroll
            for (int r = 0; r < 4; ++r)
                rs[r] += __shfl_xor(rs[r], off, 64);
        }
        #pragma unroll
        for (int r = 0; r < 4; ++r) l_r[r] = l_r[r] * alpha[r] + rs[r];
        #pragma unroll
        for (int cb = 0; cb < 16; ++cb) {
            #pragma unroll
            for (int r = 0; r < 4; ++r) O[cb][r] *= alpha[r];
        }
        // ---- P: C-layout -> LDS -> A-layout (per-wave, waitcnt only)
        #pragma unroll
        for (int jb = 0; jb < 4; ++jb) {
            #pragma unroll
            for (int r = 0; r < 4; ++r)
                pb[(quad * 4 + r) * 72 + jb * 16 + n16] = f32_to_bf16_rn(s[jb][r]);
        }
        asm volatile("s_waitcnt lgkmcnt(0)" ::: "memory");
        bf16x8 P0 = *(const bf16x8*)(pb + n16 * 72 + quad * 8);
        bf16x8 P1 = *(const bf16x8*)(pb + n16 * 72 + 32 + quad * 8);
        // ---- O += P V : V B-frags straight from global (L1/L2-resident)
        #pragma unroll
        for (int cb = 0; cb < 16; ++cb) {
            const u16* vp = vb + (size_t)(cb * 16 + n16) * N_POS + j0 + quad * 8;
            bf16x8 v0 = *(const bf16x8*)vp;
            bf16x8 v1 = *(const bf16x8*)(vp + 32);
            O[cb] = __builtin_amdgcn_mfma_f32_16x16x32_bf16(P0, v0, O[cb], 0, 0, 0);
            O[cb] = __builtin_amdgcn_mfma_f32_16x16x32_bf16(P1, v1, O[cb], 0, 0, 0);
        }
    }

    // ---- epilogue: O/l, transpose via LDS, + residual x, coalesced store
    float inv_l[4];
    #pragma unroll
    for (int r = 0; r < 4; ++r) inv_l[r] = 1.f / l_r[r];
    float* ep = epi[wave];
    const float* xb2 = x + (size_t)b * C_DIM * N_POS;
    float* ob       = out + (size_t)b * C_DIM * N_POS;
    for (int half = 0; half < 2; ++half) {
        #pragma unroll
        for (int cbl = 0; cbl < 8; ++cbl) {
            int cb = half * 8 + cbl;
            #pragma unroll
            for (int r = 0; r < 4; ++r)
                ep[(quad * 4 + r) * 129 + cbl * 16 + n16] = O[cb][r] * inv_l[r];
        }
        asm volatile("s_waitcnt lgkmcnt(0)" ::: "memory");
        for (int it = 0; it < 32; ++it) {
            int cl = it * 4 + quad;
            int c  = half * 128 + cl;
            float val = ep[n16 * 129 + cl];
            size_t g = (size_t)c * N_POS + i0 + n16;
            ob[g] = val + xb2[g];
        }
        asm volatile("s_waitcnt lgkmcnt(0)" ::: "memory");
    }
}

extern "C" void kernel_launch(void* const* d_in, const int* in_sizes, int n_in,
                              void* d_out, int out_size, void* d_ws, size_t ws_size,
                              hipStream_t stream) {
    const float* x  = (const float*)d_in[0];
    const float* Wq = (const float*)d_in[1];
    const float* bq = (const float*)d_in[2];
    const float* Wk = (const float*)d_in[3];
    const float* bk = (const float*)d_in[4];
    const float* Wv = (const float*)d_in[5];
    const float* bv = (const float*)d_in[6];
    float* out = (float*)d_out;

    // workspace layout (12.5 MB total):
    //   qhi/qlo/khi/klo: [B,N,32] bf16, 1 MB each; vbf: [B,C,N] bf16, 8 MB
    char* ws = (char*)d_ws;
    u16* qhi = (u16*)(ws);
    u16* qlo = (u16*)(ws + (1u << 20));
    u16* khi = (u16*)(ws + (2u << 20));
    u16* klo = (u16*)(ws + (3u << 20));
    u16* vbf = (u16*)(ws + (4u << 20));

    hipLaunchKernelGGL(proj_kernel, dim3(512), dim3(256), 0, stream,
                       x, Wq, bq, Wk, bk, Wv, bv, qhi, qlo, khi, klo, vbf);
    hipLaunchKernelGGL(flash_kernel, dim3(256), dim3(256), 0, stream,
                       qhi, qlo, khi, klo, vbf, x, out);
}